// Round 14
// baseline (448.571 us; speedup 1.0000x reference)
//
#include <hip/hip_runtime.h>

#define C_    256
#define DHW   110592
#define NTOK  221184   // B * DHW
#define NSEQ  216      // tokens per window
#define NH    8
#define DH    32

typedef _Float16 half8  __attribute__((ext_vector_type(8)));
typedef _Float16 half4v __attribute__((ext_vector_type(4)));
typedef __fp16   fp16x2 __attribute__((ext_vector_type(2)));
typedef float    float4v  __attribute__((ext_vector_type(4)));
typedef float    float16v __attribute__((ext_vector_type(16)));

union H8U4 { half8 h; uint4 u; };
union H2U1 { fp16x2 h; unsigned u; };

static __device__ __forceinline__ unsigned pkrtz(float a, float b) {
    H2U1 t; t.h = __builtin_amdgcn_cvt_pkrtz(a, b); return t.u;
}

// ---------------- Kernel 0: convert proj_w fp32 -> fp16 ----------------
__global__ __launch_bounds__(256) void k_convert_w(const float* __restrict__ w,
                                                   _Float16* __restrict__ wh) {
    int i = blockIdx.x * 256 + threadIdx.x;
#pragma unroll
    for (int j = 0; j < 4; ++j) {
        int idx = i + j * 16384;
        wh[idx] = (_Float16)w[idx];
    }
}

// ---------------- Kernel 1: window-partition + LayerNorm (round-9 best: 239us) ----
__global__ __launch_bounds__(512, 2) void k_ln(
    const float* __restrict__ q_map, const float* __restrict__ k_map,
    const float* __restrict__ v_map,
    const float* __restrict__ lnq_w, const float* __restrict__ lnq_b,
    const float* __restrict__ lnkv_w, const float* __restrict__ lnkv_b,
    _Float16* __restrict__ qo, _Float16* __restrict__ ko, _Float16* __restrict__ vo)
{
    __shared__ alignas(16) float ps1[8][64];
    __shared__ alignas(16) float ps2[8][64];
    const int tid = threadIdx.x;
    const int tx = tid & 15;    // token quad: tokens tx*4 .. tx*4+3
    const int cg = tid >> 4;    // channel group: channels cg*8 .. cg*8+7 (0..31)
    const int wv_ = tid >> 6;   // wave 0..7
    const int lane = tid & 63;
    const int m = blockIdx.y;
    const float* xm = (m == 0) ? q_map : (m == 1) ? k_map : v_map;
    _Float16*   xo = (m == 0) ? qo    : (m == 1) ? ko    : vo;
    const float* wvp = (m == 0) ? lnq_w : lnkv_w;
    const float* bvp = (m == 0) ? lnq_b : lnkv_b;
    const float sc = (m == 0) ? (0.17677669529663687f * 1.4426950408889634f) : 1.0f;

    const long pg = (long)blockIdx.x * 64;
    const int b = (int)(pg / DHW);
    const int pos = (int)(pg - (long)b * DHW);

    const float* xp = xm + (size_t)b * C_ * DHW + pos + tx * 4;
    float4 x[8];
    float4v s1{}, s2{};
#pragma unroll
    for (int i = 0; i < 8; ++i) {
        x[i] = *(const float4*)(xp + (size_t)(cg * 8 + i) * DHW);
        s1[0] += x[i].x; s2[0] = fmaf(x[i].x, x[i].x, s2[0]);
        s1[1] += x[i].y; s2[1] = fmaf(x[i].y, x[i].y, s2[1]);
        s1[2] += x[i].z; s2[2] = fmaf(x[i].z, x[i].z, s2[2]);
        s1[3] += x[i].w; s2[3] = fmaf(x[i].w, x[i].w, s2[3]);
    }
#pragma unroll
    for (int i = 0; i < 8; ++i)
        asm volatile("" : "+v"(x[i].x), "+v"(x[i].y), "+v"(x[i].z), "+v"(x[i].w));

#pragma unroll
    for (int j = 0; j < 4; ++j) {
        s1[j] += __shfl_xor(s1[j], 16);
        s2[j] += __shfl_xor(s2[j], 16);
        s1[j] += __shfl_xor(s1[j], 32);
        s2[j] += __shfl_xor(s2[j], 32);
    }
    if (lane < 16) {
        *(float4v*)(&ps1[wv_][tx * 4]) = s1;
        *(float4v*)(&ps2[wv_][tx * 4]) = s2;
    }
    __syncthreads();

    float4v a1{}, a2{};
#pragma unroll
    for (int w = 0; w < 8; ++w) {
        float4v t1 = *(const float4v*)(&ps1[w][tx * 4]);
        float4v t2 = *(const float4v*)(&ps2[w][tx * 4]);
#pragma unroll
        for (int j = 0; j < 4; ++j) { a1[j] += t1[j]; a2[j] += t2[j]; }
    }
    float mu[4], rs[4];
#pragma unroll
    for (int j = 0; j < 4; ++j) {
        mu[j] = a1[j] * (1.f / 256.f);
        rs[j] = rsqrtf(a2[j] * (1.f / 256.f) - mu[j] * mu[j] + 1e-5f);
    }

    float wr[8], br[8];
#pragma unroll
    for (int cc = 0; cc < 2; ++cc) {
        float4 wq = *(const float4*)(wvp + cg * 8 + cc * 4);
        float4 bq = *(const float4*)(bvp + cg * 8 + cc * 4);
        wr[cc * 4 + 0] = wq.x * sc; br[cc * 4 + 0] = bq.x * sc;
        wr[cc * 4 + 1] = wq.y * sc; br[cc * 4 + 1] = bq.y * sc;
        wr[cc * 4 + 2] = wq.z * sc; br[cc * 4 + 2] = bq.z * sc;
        wr[cc * 4 + 3] = wq.w * sc; br[cc * 4 + 3] = bq.w * sc;
    }

#pragma unroll
    for (int j = 0; j < 4; ++j) {
        const int p = pos + tx * 4 + j;
        const int d = p / 2304, rem = p % 2304, hh = rem / 48, ww = rem % 48;
        const int wi = (d / 6) * 64 + (hh / 6) * 8 + (ww / 6);
        const int n = (d % 6) * 36 + (hh % 6) * 6 + (ww % 6);
        _Float16* op = xo + ((size_t)(b * 512 + wi) * NSEQ + n) * C_ + cg * 8;
        half8 y;
#pragma unroll
        for (int i = 0; i < 8; ++i) {
            float xa = (j == 0) ? x[i].x : (j == 1) ? x[i].y : (j == 2) ? x[i].z : x[i].w;
            y[i] = (_Float16)((xa - mu[j]) * rs[j] * wr[i] + br[i]);
        }
        *(half8*)op = y;
    }
}

// ---------------- Kernel 2: per-(window, head) attention, 32x32 MFMA ----------------
__global__ __launch_bounds__(448) void k_attn(
    const _Float16* __restrict__ qh, const _Float16* __restrict__ kh,
    const _Float16* __restrict__ vh, _Float16* __restrict__ ao)
{
    __shared__ _Float16 Ks[224 * 32];   // [k][d], 16B cols swizzled by ((k>>1)&3)
    __shared__ _Float16 Vb[28 * 256];   // [kblk][d][8]
    __shared__ float rsum[7 * 32];

    const int tid = threadIdx.x;
    const int wave = tid >> 6, lane = tid & 63;
    const int l31 = lane & 31, h = lane >> 5;
    const int o = ((blockIdx.x & 7) << 10) | (blockIdx.x >> 3);
    const int win = o >> 3, head = o & 7;
    const size_t base = ((size_t)win * NSEQ) * C_ + head * DH;

#pragma unroll
    for (int it = 0; it < 2; ++it) {
        int idx = tid + it * 448;
        int r = idx >> 2, c8 = idx & 3;
        half8 kv{};
        if (r < NSEQ) kv = *(const half8*)(kh + base + (size_t)r * C_ + c8 * 8);
        *(half8*)(&Ks[r * 32 + ((c8 ^ ((r >> 1) & 3)) * 8)]) = kv;
    }
#pragma unroll
    for (int it = 0; it < 2; ++it) {
        int idx = tid + it * 448;
        int kb = idx >> 5, d = idx & 31;
        const _Float16* vp = vh + base + (size_t)(kb * 8) * C_ + d;
        half8 vv{};
#pragma unroll
        for (int j = 0; j < 8; ++j) {
            int r = kb * 8 + j;
            vv[j] = (r < NSEQ) ? vp[(size_t)j * C_] : (_Float16)0;
        }
        *(half8*)(&Vb[kb * 256 + d * 8]) = vv;
    }

    const int qrow = wave * 32 + l31;
    half8 qf0{}, qf1{};
    if (qrow < NSEQ) {
        const _Float16* qp = qh + base + (size_t)qrow * C_ + h * 8;
        qf0 = *(const half8*)(qp);
        qf1 = *(const half8*)(qp + 16);
    }
    __syncthreads();

    float16v O{};
    float sum = 0.f;

#pragma unroll
    for (int kt = 0; kt < 7; ++kt) {
        const int krow = kt * 32 + l31;
        const int sw = (krow >> 1) & 3;
        half8 kf0 = *(const half8*)(&Ks[krow * 32 + ((h ^ sw) * 8)]);
        half8 kf1 = *(const half8*)(&Ks[krow * 32 + (((2 + h) ^ sw) * 8)]);
        float16v s{};
        s = __builtin_amdgcn_mfma_f32_32x32x16_f16(kf0, qf0, s, 0, 0, 0);
        s = __builtin_amdgcn_mfma_f32_32x32x16_f16(kf1, qf1, s, 0, 0, 0);

        const int RV = (kt == 6) ? 12 : 16;
        float p[16];
#pragma unroll
        for (int r = 0; r < 16; ++r) p[r] = (r < RV) ? exp2f(s[r]) : 0.f;
#pragma unroll
        for (int r = 0; r < 16; ++r) sum += p[r];

#pragma unroll
        for (int m = 0; m < 2; ++m) {
            const int rb = m * 8;
            unsigned a0 = pkrtz(p[rb + 0], p[rb + 1]);
            unsigned a1 = pkrtz(p[rb + 2], p[rb + 3]);
            unsigned a2 = pkrtz(p[rb + 4], p[rb + 5]);
            unsigned a3 = pkrtz(p[rb + 6], p[rb + 7]);
            asm volatile("v_permlane32_swap_b32 %0, %1" : "+v"(a0), "+v"(a2));
            asm volatile("v_permlane32_swap_b32 %0, %1" : "+v"(a1), "+v"(a3));
            H8U4 pa;
            pa.u.x = a0; pa.u.y = a1; pa.u.z = a2; pa.u.w = a3;
            half8 vb = *(const half8*)(&Vb[(kt * 4 + m * 2 + h) * 256 + l31 * 8]);
            O = __builtin_amdgcn_mfma_f32_32x32x16_f16(pa.h, vb, O, 0, 0, 0);
        }
    }

    float tot = sum + __shfl_xor(sum, 32);
    if (h == 0) rsum[wave * 32 + l31] = 1.f / tot;
    __syncthreads();

    float4 r0 = *(const float4*)(&rsum[wave * 32 + 4 * h + 0]);
    float4 r1 = *(const float4*)(&rsum[wave * 32 + 4 * h + 8]);
    float4 r2 = *(const float4*)(&rsum[wave * 32 + 4 * h + 16]);
    float4 r3 = *(const float4*)(&rsum[wave * 32 + 4 * h + 24]);
    float rv[16] = {r0.x, r0.y, r0.z, r0.w, r1.x, r1.y, r1.z, r1.w,
                    r2.x, r2.y, r2.z, r2.w, r3.x, r3.y, r3.z, r3.w};

    _Float16* aop = ao + ((size_t)win * NSEQ + wave * 32) * C_ + head * DH + l31;
#pragma unroll
    for (int r = 0; r < 16; ++r) {
        int qp = (r & 3) + 8 * (r >> 2) + 4 * h;
        if (wave * 32 + qp < NSEQ)
            aop[(size_t)qp * C_] = (_Float16)(O[r] * rv[r]);
    }
}

// ---------------- Kernel 3: projection GEMM + bias + window reverse ----------------
// New epilogue: per-wave LDS transpose Ot[16ch][68] so output stores are
// 4 planes x 256B contiguous per instruction (dwordx4/lane) instead of 16x64B.
__global__ __launch_bounds__(256) void k_proj(
    const _Float16* __restrict__ ah, const _Float16* __restrict__ wh,
    const float* __restrict__ pb, float* __restrict__ out)
{
    __shared__ _Float16 As[64 * 264];
    __shared__ alignas(16) float Ot[4][16 * 68];
    const int tid = threadIdx.x;
    const int wave = tid >> 6, lane = tid & 63;
    const int l15 = lane & 15, g = lane >> 4;
    const long tok0 = (long)blockIdx.x * 64;

    {
        int r = tid >> 2, c8 = tid & 3;
        long tok = tok0 + r;
        int b = (int)(tok / DHW);
        int pos = (int)(tok - (long)b * DHW);
        int d = pos / 2304, rem = pos % 2304, hh = rem / 48, ww = rem % 48;
        int wi = (d / 6) * 64 + (hh / 6) * 8 + (ww / 6);
        int n = (d % 6) * 36 + (hh % 6) * 6 + (ww % 6);
        const _Float16* src = ah + ((size_t)(b * 512 + wi) * NSEQ + n) * C_;
        _Float16* dst = &As[r * 264];
#pragma unroll
        for (int i = 0; i < 8; ++i)
            *(half8*)(dst + c8 * 8 + i * 32) = *(const half8*)(src + c8 * 8 + i * 32);
    }
    __syncthreads();

    const int b0 = (int)(tok0 / DHW);
    const int pos0 = (int)(tok0 - (long)b0 * DHW);
    float* ob = out + (size_t)b0 * C_ * DHW + pos0;
    float* ow = &Ot[wave][0];

#pragma unroll
    for (int ct = 0; ct < 4; ++ct) {
        const int c0 = wave * 64 + ct * 16;
        half8 afr[8];
#pragma unroll
        for (int kc = 0; kc < 8; ++kc)
            afr[kc] = *(const half8*)(wh + (size_t)(c0 + l15) * C_ + kc * 32 + g * 8);
        float4 bq = *(const float4*)(pb + c0 + g * 4);
#pragma unroll
        for (int tt = 0; tt < 4; ++tt) {
            float4v o = {bq.x, bq.y, bq.z, bq.w};
#pragma unroll
            for (int kc = 0; kc < 8; ++kc) {
                half8 bfr = *(const half8*)(&As[(tt * 16 + l15) * 264 + kc * 32 + g * 8]);
                o = __builtin_amdgcn_mfma_f32_16x16x32_f16(afr[kc], bfr, o, 0, 0, 0);
            }
            // transpose-store into this wave's Ot: [local ch g*4+r][token tt*16+l15]
#pragma unroll
            for (int r = 0; r < 4; ++r)
                ow[(g * 4 + r) * 68 + tt * 16 + l15] = o[r];
        }
        // within-wave LDS RAW: DS pipe is in-order per wave; wait + pin schedule
        asm volatile("s_waitcnt lgkmcnt(0)" ::: "memory");
        __builtin_amdgcn_sched_barrier(0);
        // flush: lane reads float4 (4 consecutive tokens) of channel g+4*it
#pragma unroll
        for (int it = 0; it < 4; ++it) {
            const int chl = g + 4 * it;
            float4 v = *(const float4*)(&ow[chl * 68 + l15 * 4]);
            *(float4*)(ob + (size_t)(c0 + chl) * DHW + l15 * 4) = v;
        }
        __builtin_amdgcn_sched_barrier(0);
    }
}

extern "C" void kernel_launch(void* const* d_in, const int* in_sizes, int n_in,
                              void* d_out, int out_size, void* d_ws, size_t ws_size,
                              hipStream_t stream)
{
    const float* q_map  = (const float*)d_in[0];
    const float* k_map  = (const float*)d_in[1];
    const float* v_map  = (const float*)d_in[2];
    const float* lnq_w  = (const float*)d_in[3];
    const float* lnq_b  = (const float*)d_in[4];
    const float* lnkv_w = (const float*)d_in[5];
    const float* lnkv_b = (const float*)d_in[6];
    const float* proj_w = (const float*)d_in[7];
    const float* proj_b = (const float*)d_in[8];
    float* out = (float*)d_out;

    const size_t SZ = (size_t)NTOK * C_;
    _Float16* qh = (_Float16*)d_ws;
    _Float16* kh = qh + SZ;
    _Float16* vh = kh + SZ;
    _Float16* ah = vh + SZ;
    _Float16* wh = ah + SZ;

    k_convert_w<<<64, 256, 0, stream>>>(proj_w, wh);
    k_ln<<<dim3(3456, 3), 512, 0, stream>>>(q_map, k_map, v_map,
                                            lnq_w, lnq_b, lnkv_w, lnkv_b, qh, kh, vh);
    k_attn<<<8192, 448, 0, stream>>>(qh, kh, vh, ah);
    k_proj<<<3456, 256, 0, stream>>>(ah, wh, proj_b, out);
}

// Round 15
// 447.958 us; speedup vs baseline: 1.0014x; 1.0014x over previous
//
#include <hip/hip_runtime.h>

#define C_    256
#define DHW   110592
#define NTOK  221184   // B * DHW
#define NSEQ  216      // tokens per window
#define NH    8
#define DH    32

typedef _Float16 half8  __attribute__((ext_vector_type(8)));
typedef _Float16 half4v __attribute__((ext_vector_type(4)));
typedef __fp16   fp16x2 __attribute__((ext_vector_type(2)));
typedef float    float4v  __attribute__((ext_vector_type(4)));
typedef float    float16v __attribute__((ext_vector_type(16)));

union H8U4 { half8 h; uint4 u; };
union H2U1 { fp16x2 h; unsigned u; };

static __device__ __forceinline__ unsigned pkrtz(float a, float b) {
    H2U1 t; t.h = __builtin_amdgcn_cvt_pkrtz(a, b); return t.u;
}

// ---------------- Kernel 0: convert proj_w fp32 -> fp16 ----------------
__global__ __launch_bounds__(256) void k_convert_w(const float* __restrict__ w,
                                                   _Float16* __restrict__ wh) {
    int i = blockIdx.x * 256 + threadIdx.x;
#pragma unroll
    for (int j = 0; j < 4; ++j) {
        int idx = i + j * 16384;
        wh[idx] = (_Float16)w[idx];
    }
}

// ---------------- Kernel 1: window-partition + LayerNorm (round-9 best: 239us) ----
__global__ __launch_bounds__(512, 2) void k_ln(
    const float* __restrict__ q_map, const float* __restrict__ k_map,
    const float* __restrict__ v_map,
    const float* __restrict__ lnq_w, const float* __restrict__ lnq_b,
    const float* __restrict__ lnkv_w, const float* __restrict__ lnkv_b,
    _Float16* __restrict__ qo, _Float16* __restrict__ ko, _Float16* __restrict__ vo)
{
    __shared__ alignas(16) float ps1[8][64];
    __shared__ alignas(16) float ps2[8][64];
    const int tid = threadIdx.x;
    const int tx = tid & 15;    // token quad: tokens tx*4 .. tx*4+3
    const int cg = tid >> 4;    // channel group: channels cg*8 .. cg*8+7 (0..31)
    const int wv_ = tid >> 6;   // wave 0..7
    const int lane = tid & 63;
    const int m = blockIdx.y;
    const float* xm = (m == 0) ? q_map : (m == 1) ? k_map : v_map;
    _Float16*   xo = (m == 0) ? qo    : (m == 1) ? ko    : vo;
    const float* wvp = (m == 0) ? lnq_w : lnkv_w;
    const float* bvp = (m == 0) ? lnq_b : lnkv_b;
    const float sc = (m == 0) ? (0.17677669529663687f * 1.4426950408889634f) : 1.0f;

    const long pg = (long)blockIdx.x * 64;
    const int b = (int)(pg / DHW);
    const int pos = (int)(pg - (long)b * DHW);

    const float* xp = xm + (size_t)b * C_ * DHW + pos + tx * 4;
    float4 x[8];
    float4v s1{}, s2{};
#pragma unroll
    for (int i = 0; i < 8; ++i) {
        x[i] = *(const float4*)(xp + (size_t)(cg * 8 + i) * DHW);
        s1[0] += x[i].x; s2[0] = fmaf(x[i].x, x[i].x, s2[0]);
        s1[1] += x[i].y; s2[1] = fmaf(x[i].y, x[i].y, s2[1]);
        s1[2] += x[i].z; s2[2] = fmaf(x[i].z, x[i].z, s2[2]);
        s1[3] += x[i].w; s2[3] = fmaf(x[i].w, x[i].w, s2[3]);
    }
#pragma unroll
    for (int i = 0; i < 8; ++i)
        asm volatile("" : "+v"(x[i].x), "+v"(x[i].y), "+v"(x[i].z), "+v"(x[i].w));

#pragma unroll
    for (int j = 0; j < 4; ++j) {
        s1[j] += __shfl_xor(s1[j], 16);
        s2[j] += __shfl_xor(s2[j], 16);
        s1[j] += __shfl_xor(s1[j], 32);
        s2[j] += __shfl_xor(s2[j], 32);
    }
    if (lane < 16) {
        *(float4v*)(&ps1[wv_][tx * 4]) = s1;
        *(float4v*)(&ps2[wv_][tx * 4]) = s2;
    }
    __syncthreads();

    float4v a1{}, a2{};
#pragma unroll
    for (int w = 0; w < 8; ++w) {
        float4v t1 = *(const float4v*)(&ps1[w][tx * 4]);
        float4v t2 = *(const float4v*)(&ps2[w][tx * 4]);
#pragma unroll
        for (int j = 0; j < 4; ++j) { a1[j] += t1[j]; a2[j] += t2[j]; }
    }
    float mu[4], rs[4];
#pragma unroll
    for (int j = 0; j < 4; ++j) {
        mu[j] = a1[j] * (1.f / 256.f);
        rs[j] = rsqrtf(a2[j] * (1.f / 256.f) - mu[j] * mu[j] + 1e-5f);
    }

    float wr[8], br[8];
#pragma unroll
    for (int cc = 0; cc < 2; ++cc) {
        float4 wq = *(const float4*)(wvp + cg * 8 + cc * 4);
        float4 bq = *(const float4*)(bvp + cg * 8 + cc * 4);
        wr[cc * 4 + 0] = wq.x * sc; br[cc * 4 + 0] = bq.x * sc;
        wr[cc * 4 + 1] = wq.y * sc; br[cc * 4 + 1] = bq.y * sc;
        wr[cc * 4 + 2] = wq.z * sc; br[cc * 4 + 2] = bq.z * sc;
        wr[cc * 4 + 3] = wq.w * sc; br[cc * 4 + 3] = bq.w * sc;
    }

#pragma unroll
    for (int j = 0; j < 4; ++j) {
        const int p = pos + tx * 4 + j;
        const int d = p / 2304, rem = p % 2304, hh = rem / 48, ww = rem % 48;
        const int wi = (d / 6) * 64 + (hh / 6) * 8 + (ww / 6);
        const int n = (d % 6) * 36 + (hh % 6) * 6 + (ww % 6);
        _Float16* op = xo + ((size_t)(b * 512 + wi) * NSEQ + n) * C_ + cg * 8;
        half8 y;
#pragma unroll
        for (int i = 0; i < 8; ++i) {
            float xa = (j == 0) ? x[i].x : (j == 1) ? x[i].y : (j == 2) ? x[i].z : x[i].w;
            y[i] = (_Float16)((xa - mu[j]) * rs[j] * wr[i] + br[i]);
        }
        *(half8*)op = y;
    }
}

// ---------------- Kernel 2: per-(window, head) attention, 32x32 MFMA ----------------
__global__ __launch_bounds__(448) void k_attn(
    const _Float16* __restrict__ qh, const _Float16* __restrict__ kh,
    const _Float16* __restrict__ vh, _Float16* __restrict__ ao)
{
    __shared__ _Float16 Ks[224 * 32];   // [k][d], 16B cols swizzled by ((k>>1)&3)
    __shared__ _Float16 Vb[28 * 256];   // [kblk][d][8]
    __shared__ float rsum[7 * 32];

    const int tid = threadIdx.x;
    const int wave = tid >> 6, lane = tid & 63;
    const int l31 = lane & 31, h = lane >> 5;
    const int o = ((blockIdx.x & 7) << 10) | (blockIdx.x >> 3);
    const int win = o >> 3, head = o & 7;
    const size_t base = ((size_t)win * NSEQ) * C_ + head * DH;

#pragma unroll
    for (int it = 0; it < 2; ++it) {
        int idx = tid + it * 448;
        int r = idx >> 2, c8 = idx & 3;
        half8 kv{};
        if (r < NSEQ) kv = *(const half8*)(kh + base + (size_t)r * C_ + c8 * 8);
        *(half8*)(&Ks[r * 32 + ((c8 ^ ((r >> 1) & 3)) * 8)]) = kv;
    }
#pragma unroll
    for (int it = 0; it < 2; ++it) {
        int idx = tid + it * 448;
        int kb = idx >> 5, d = idx & 31;
        const _Float16* vp = vh + base + (size_t)(kb * 8) * C_ + d;
        half8 vv{};
#pragma unroll
        for (int j = 0; j < 8; ++j) {
            int r = kb * 8 + j;
            vv[j] = (r < NSEQ) ? vp[(size_t)j * C_] : (_Float16)0;
        }
        *(half8*)(&Vb[kb * 256 + d * 8]) = vv;
    }

    const int qrow = wave * 32 + l31;
    half8 qf0{}, qf1{};
    if (qrow < NSEQ) {
        const _Float16* qp = qh + base + (size_t)qrow * C_ + h * 8;
        qf0 = *(const half8*)(qp);
        qf1 = *(const half8*)(qp + 16);
    }
    __syncthreads();

    float16v O{};
    float sum = 0.f;

#pragma unroll
    for (int kt = 0; kt < 7; ++kt) {
        const int krow = kt * 32 + l31;
        const int sw = (krow >> 1) & 3;
        half8 kf0 = *(const half8*)(&Ks[krow * 32 + ((h ^ sw) * 8)]);
        half8 kf1 = *(const half8*)(&Ks[krow * 32 + (((2 + h) ^ sw) * 8)]);
        float16v s{};
        s = __builtin_amdgcn_mfma_f32_32x32x16_f16(kf0, qf0, s, 0, 0, 0);
        s = __builtin_amdgcn_mfma_f32_32x32x16_f16(kf1, qf1, s, 0, 0, 0);

        const int RV = (kt == 6) ? 12 : 16;
        float p[16];
#pragma unroll
        for (int r = 0; r < 16; ++r) p[r] = (r < RV) ? exp2f(s[r]) : 0.f;
#pragma unroll
        for (int r = 0; r < 16; ++r) sum += p[r];

#pragma unroll
        for (int m = 0; m < 2; ++m) {
            const int rb = m * 8;
            unsigned a0 = pkrtz(p[rb + 0], p[rb + 1]);
            unsigned a1 = pkrtz(p[rb + 2], p[rb + 3]);
            unsigned a2 = pkrtz(p[rb + 4], p[rb + 5]);
            unsigned a3 = pkrtz(p[rb + 6], p[rb + 7]);
            asm volatile("v_permlane32_swap_b32 %0, %1" : "+v"(a0), "+v"(a2));
            asm volatile("v_permlane32_swap_b32 %0, %1" : "+v"(a1), "+v"(a3));
            H8U4 pa;
            pa.u.x = a0; pa.u.y = a1; pa.u.z = a2; pa.u.w = a3;
            half8 vb = *(const half8*)(&Vb[(kt * 4 + m * 2 + h) * 256 + l31 * 8]);
            O = __builtin_amdgcn_mfma_f32_32x32x16_f16(pa.h, vb, O, 0, 0, 0);
        }
    }

    float tot = sum + __shfl_xor(sum, 32);
    if (h == 0) rsum[wave * 32 + l31] = 1.f / tot;
    __syncthreads();

    float4 r0 = *(const float4*)(&rsum[wave * 32 + 4 * h + 0]);
    float4 r1 = *(const float4*)(&rsum[wave * 32 + 4 * h + 8]);
    float4 r2 = *(const float4*)(&rsum[wave * 32 + 4 * h + 16]);
    float4 r3 = *(const float4*)(&rsum[wave * 32 + 4 * h + 24]);
    float rv[16] = {r0.x, r0.y, r0.z, r0.w, r1.x, r1.y, r1.z, r1.w,
                    r2.x, r2.y, r2.z, r2.w, r3.x, r3.y, r3.z, r3.w};

    _Float16* aop = ao + ((size_t)win * NSEQ + wave * 32) * C_ + head * DH + l31;
#pragma unroll
    for (int r = 0; r < 16; ++r) {
        int qp = (r & 3) + 8 * (r >> 2) + 4 * h;
        if (wave * 32 + qp < NSEQ)
            aop[(size_t)qp * C_] = (_Float16)(O[r] * rv[r]);
    }
}

// ---------------- Kernel 3: projection GEMM + bias + window reverse ----------------
// New epilogue: per-wave LDS transpose Ot[16ch][68] so output stores are
// 4 planes x 256B contiguous per instruction (dwordx4/lane) instead of 16x64B.
__global__ __launch_bounds__(256) void k_proj(
    const _Float16* __restrict__ ah, const _Float16* __restrict__ wh,
    const float* __restrict__ pb, float* __restrict__ out)
{
    __shared__ _Float16 As[64 * 264];
    __shared__ alignas(16) float Ot[4][16 * 68];
    const int tid = threadIdx.x;
    const int wave = tid >> 6, lane = tid & 63;
    const int l15 = lane & 15, g = lane >> 4;
    const long tok0 = (long)blockIdx.x * 64;

    {
        int r = tid >> 2, c8 = tid & 3;
        long tok = tok0 + r;
        int b = (int)(tok / DHW);
        int pos = (int)(tok - (long)b * DHW);
        int d = pos / 2304, rem = pos % 2304, hh = rem / 48, ww = rem % 48;
        int wi = (d / 6) * 64 + (hh / 6) * 8 + (ww / 6);
        int n = (d % 6) * 36 + (hh % 6) * 6 + (ww % 6);
        const _Float16* src = ah + ((size_t)(b * 512 + wi) * NSEQ + n) * C_;
        _Float16* dst = &As[r * 264];
#pragma unroll
        for (int i = 0; i < 8; ++i)
            *(half8*)(dst + c8 * 8 + i * 32) = *(const half8*)(src + c8 * 8 + i * 32);
    }
    __syncthreads();

    const int b0 = (int)(tok0 / DHW);
    const int pos0 = (int)(tok0 - (long)b0 * DHW);
    float* ob = out + (size_t)b0 * C_ * DHW + pos0;
    float* ow = &Ot[wave][0];

#pragma unroll
    for (int ct = 0; ct < 4; ++ct) {
        const int c0 = wave * 64 + ct * 16;
        half8 afr[8];
#pragma unroll
        for (int kc = 0; kc < 8; ++kc)
            afr[kc] = *(const half8*)(wh + (size_t)(c0 + l15) * C_ + kc * 32 + g * 8);
        float4 bq = *(const float4*)(pb + c0 + g * 4);
#pragma unroll
        for (int tt = 0; tt < 4; ++tt) {
            float4v o = {bq.x, bq.y, bq.z, bq.w};
#pragma unroll
            for (int kc = 0; kc < 8; ++kc) {
                half8 bfr = *(const half8*)(&As[(tt * 16 + l15) * 264 + kc * 32 + g * 8]);
                o = __builtin_amdgcn_mfma_f32_16x16x32_f16(afr[kc], bfr, o, 0, 0, 0);
            }
            // transpose-store into this wave's Ot: [local ch g*4+r][token tt*16+l15]
#pragma unroll
            for (int r = 0; r < 4; ++r)
                ow[(g * 4 + r) * 68 + tt * 16 + l15] = o[r];
        }
        // within-wave LDS RAW: DS pipe is in-order per wave; wait + pin schedule
        asm volatile("s_waitcnt lgkmcnt(0)" ::: "memory");
        __builtin_amdgcn_sched_barrier(0);
        // flush: lane reads float4 (4 consecutive tokens) of channel g+4*it
#pragma unroll
        for (int it = 0; it < 4; ++it) {
            const int chl = g + 4 * it;
            float4 v = *(const float4*)(&ow[chl * 68 + l15 * 4]);
            *(float4*)(ob + (size_t)(c0 + chl) * DHW + l15 * 4) = v;
        }
        __builtin_amdgcn_sched_barrier(0);
    }
}

extern "C" void kernel_launch(void* const* d_in, const int* in_sizes, int n_in,
                              void* d_out, int out_size, void* d_ws, size_t ws_size,
                              hipStream_t stream)
{
    const float* q_map  = (const float*)d_in[0];
    const float* k_map  = (const float*)d_in[1];
    const float* v_map  = (const float*)d_in[2];
    const float* lnq_w  = (const float*)d_in[3];
    const float* lnq_b  = (const float*)d_in[4];
    const float* lnkv_w = (const float*)d_in[5];
    const float* lnkv_b = (const float*)d_in[6];
    const float* proj_w = (const float*)d_in[7];
    const float* proj_b = (const float*)d_in[8];
    float* out = (float*)d_out;

    const size_t SZ = (size_t)NTOK * C_;
    _Float16* qh = (_Float16*)d_ws;
    _Float16* kh = qh + SZ;
    _Float16* vh = kh + SZ;
    _Float16* ah = vh + SZ;
    _Float16* wh = ah + SZ;

    k_convert_w<<<64, 256, 0, stream>>>(proj_w, wh);
    k_ln<<<dim3(3456, 3), 512, 0, stream>>>(q_map, k_map, v_map,
                                            lnq_w, lnq_b, lnkv_w, lnkv_b, qh, kh, vh);
    k_attn<<<8192, 448, 0, stream>>>(qh, kh, vh, ah);
    k_proj<<<3456, 256, 0, stream>>>(ah, wh, proj_b, out);
}

// Round 16
// 447.284 us; speedup vs baseline: 1.0029x; 1.0015x over previous
//
#include <hip/hip_runtime.h>

#define C_    256
#define DHW   110592
#define NTOK  221184   // B * DHW
#define NSEQ  216      // tokens per window
#define NH    8
#define DH    32

typedef _Float16 half8  __attribute__((ext_vector_type(8)));
typedef _Float16 half4v __attribute__((ext_vector_type(4)));
typedef __fp16   fp16x2 __attribute__((ext_vector_type(2)));
typedef float    float4v  __attribute__((ext_vector_type(4)));
typedef float    float16v __attribute__((ext_vector_type(16)));

union H8U4 { half8 h; uint4 u; };
union H2U1 { fp16x2 h; unsigned u; };

static __device__ __forceinline__ unsigned pkrtz(float a, float b) {
    H2U1 t; t.h = __builtin_amdgcn_cvt_pkrtz(a, b); return t.u;
}

// ---------------- Kernel 0: convert proj_w fp32 -> fp16 ----------------
__global__ __launch_bounds__(256) void k_convert_w(const float* __restrict__ w,
                                                   _Float16* __restrict__ wh) {
    int i = blockIdx.x * 256 + threadIdx.x;
#pragma unroll
    for (int j = 0; j < 4; ++j) {
        int idx = i + j * 16384;
        wh[idx] = (_Float16)w[idx];
    }
}

// ---------------- Kernel 1: window-partition + LayerNorm (round-9 best: 239us) ----
__global__ __launch_bounds__(512, 2) void k_ln(
    const float* __restrict__ q_map, const float* __restrict__ k_map,
    const float* __restrict__ v_map,
    const float* __restrict__ lnq_w, const float* __restrict__ lnq_b,
    const float* __restrict__ lnkv_w, const float* __restrict__ lnkv_b,
    _Float16* __restrict__ qo, _Float16* __restrict__ ko, _Float16* __restrict__ vo)
{
    __shared__ alignas(16) float ps1[8][64];
    __shared__ alignas(16) float ps2[8][64];
    const int tid = threadIdx.x;
    const int tx = tid & 15;    // token quad: tokens tx*4 .. tx*4+3
    const int cg = tid >> 4;    // channel group: channels cg*8 .. cg*8+7 (0..31)
    const int wv_ = tid >> 6;   // wave 0..7
    const int lane = tid & 63;
    const int m = blockIdx.y;
    const float* xm = (m == 0) ? q_map : (m == 1) ? k_map : v_map;
    _Float16*   xo = (m == 0) ? qo    : (m == 1) ? ko    : vo;
    const float* wvp = (m == 0) ? lnq_w : lnkv_w;
    const float* bvp = (m == 0) ? lnq_b : lnkv_b;
    const float sc = (m == 0) ? (0.17677669529663687f * 1.4426950408889634f) : 1.0f;

    const long pg = (long)blockIdx.x * 64;
    const int b = (int)(pg / DHW);
    const int pos = (int)(pg - (long)b * DHW);

    const float* xp = xm + (size_t)b * C_ * DHW + pos + tx * 4;
    float4 x[8];
    float4v s1{}, s2{};
#pragma unroll
    for (int i = 0; i < 8; ++i) {
        x[i] = *(const float4*)(xp + (size_t)(cg * 8 + i) * DHW);
        s1[0] += x[i].x; s2[0] = fmaf(x[i].x, x[i].x, s2[0]);
        s1[1] += x[i].y; s2[1] = fmaf(x[i].y, x[i].y, s2[1]);
        s1[2] += x[i].z; s2[2] = fmaf(x[i].z, x[i].z, s2[2]);
        s1[3] += x[i].w; s2[3] = fmaf(x[i].w, x[i].w, s2[3]);
    }
#pragma unroll
    for (int i = 0; i < 8; ++i)
        asm volatile("" : "+v"(x[i].x), "+v"(x[i].y), "+v"(x[i].z), "+v"(x[i].w));

#pragma unroll
    for (int j = 0; j < 4; ++j) {
        s1[j] += __shfl_xor(s1[j], 16);
        s2[j] += __shfl_xor(s2[j], 16);
        s1[j] += __shfl_xor(s1[j], 32);
        s2[j] += __shfl_xor(s2[j], 32);
    }
    if (lane < 16) {
        *(float4v*)(&ps1[wv_][tx * 4]) = s1;
        *(float4v*)(&ps2[wv_][tx * 4]) = s2;
    }
    __syncthreads();

    float4v a1{}, a2{};
#pragma unroll
    for (int w = 0; w < 8; ++w) {
        float4v t1 = *(const float4v*)(&ps1[w][tx * 4]);
        float4v t2 = *(const float4v*)(&ps2[w][tx * 4]);
#pragma unroll
        for (int j = 0; j < 4; ++j) { a1[j] += t1[j]; a2[j] += t2[j]; }
    }
    float mu[4], rs[4];
#pragma unroll
    for (int j = 0; j < 4; ++j) {
        mu[j] = a1[j] * (1.f / 256.f);
        rs[j] = rsqrtf(a2[j] * (1.f / 256.f) - mu[j] * mu[j] + 1e-5f);
    }

    float wr[8], br[8];
#pragma unroll
    for (int cc = 0; cc < 2; ++cc) {
        float4 wq = *(const float4*)(wvp + cg * 8 + cc * 4);
        float4 bq = *(const float4*)(bvp + cg * 8 + cc * 4);
        wr[cc * 4 + 0] = wq.x * sc; br[cc * 4 + 0] = bq.x * sc;
        wr[cc * 4 + 1] = wq.y * sc; br[cc * 4 + 1] = bq.y * sc;
        wr[cc * 4 + 2] = wq.z * sc; br[cc * 4 + 2] = bq.z * sc;
        wr[cc * 4 + 3] = wq.w * sc; br[cc * 4 + 3] = bq.w * sc;
    }

#pragma unroll
    for (int j = 0; j < 4; ++j) {
        const int p = pos + tx * 4 + j;
        const int d = p / 2304, rem = p % 2304, hh = rem / 48, ww = rem % 48;
        const int wi = (d / 6) * 64 + (hh / 6) * 8 + (ww / 6);
        const int n = (d % 6) * 36 + (hh % 6) * 6 + (ww % 6);
        _Float16* op = xo + ((size_t)(b * 512 + wi) * NSEQ + n) * C_ + cg * 8;
        half8 y;
#pragma unroll
        for (int i = 0; i < 8; ++i) {
            float xa = (j == 0) ? x[i].x : (j == 1) ? x[i].y : (j == 2) ? x[i].z : x[i].w;
            y[i] = (_Float16)((xa - mu[j]) * rs[j] * wr[i] + br[i]);
        }
        *(half8*)op = y;
    }
}

// ---------------- Kernel 2: per-(window, head) attention, 32x32 MFMA ----------------
__global__ __launch_bounds__(448) void k_attn(
    const _Float16* __restrict__ qh, const _Float16* __restrict__ kh,
    const _Float16* __restrict__ vh, _Float16* __restrict__ ao)
{
    __shared__ _Float16 Ks[224 * 32];   // [k][d], 16B cols swizzled by ((k>>1)&3)
    __shared__ _Float16 Vb[28 * 256];   // [kblk][d][8]
    __shared__ float rsum[7 * 32];

    const int tid = threadIdx.x;
    const int wave = tid >> 6, lane = tid & 63;
    const int l31 = lane & 31, h = lane >> 5;
    const int o = ((blockIdx.x & 7) << 10) | (blockIdx.x >> 3);
    const int win = o >> 3, head = o & 7;
    const size_t base = ((size_t)win * NSEQ) * C_ + head * DH;

#pragma unroll
    for (int it = 0; it < 2; ++it) {
        int idx = tid + it * 448;
        int r = idx >> 2, c8 = idx & 3;
        half8 kv{};
        if (r < NSEQ) kv = *(const half8*)(kh + base + (size_t)r * C_ + c8 * 8);
        *(half8*)(&Ks[r * 32 + ((c8 ^ ((r >> 1) & 3)) * 8)]) = kv;
    }
#pragma unroll
    for (int it = 0; it < 2; ++it) {
        int idx = tid + it * 448;
        int kb = idx >> 5, d = idx & 31;
        const _Float16* vp = vh + base + (size_t)(kb * 8) * C_ + d;
        half8 vv{};
#pragma unroll
        for (int j = 0; j < 8; ++j) {
            int r = kb * 8 + j;
            vv[j] = (r < NSEQ) ? vp[(size_t)j * C_] : (_Float16)0;
        }
        *(half8*)(&Vb[kb * 256 + d * 8]) = vv;
    }

    const int qrow = wave * 32 + l31;
    half8 qf0{}, qf1{};
    if (qrow < NSEQ) {
        const _Float16* qp = qh + base + (size_t)qrow * C_ + h * 8;
        qf0 = *(const half8*)(qp);
        qf1 = *(const half8*)(qp + 16);
    }
    __syncthreads();

    float16v O{};
    float sum = 0.f;

#pragma unroll
    for (int kt = 0; kt < 7; ++kt) {
        const int krow = kt * 32 + l31;
        const int sw = (krow >> 1) & 3;
        half8 kf0 = *(const half8*)(&Ks[krow * 32 + ((h ^ sw) * 8)]);
        half8 kf1 = *(const half8*)(&Ks[krow * 32 + (((2 + h) ^ sw) * 8)]);
        float16v s{};
        s = __builtin_amdgcn_mfma_f32_32x32x16_f16(kf0, qf0, s, 0, 0, 0);
        s = __builtin_amdgcn_mfma_f32_32x32x16_f16(kf1, qf1, s, 0, 0, 0);

        const int RV = (kt == 6) ? 12 : 16;
        float p[16];
#pragma unroll
        for (int r = 0; r < 16; ++r) p[r] = (r < RV) ? exp2f(s[r]) : 0.f;
#pragma unroll
        for (int r = 0; r < 16; ++r) sum += p[r];

#pragma unroll
        for (int m = 0; m < 2; ++m) {
            const int rb = m * 8;
            unsigned a0 = pkrtz(p[rb + 0], p[rb + 1]);
            unsigned a1 = pkrtz(p[rb + 2], p[rb + 3]);
            unsigned a2 = pkrtz(p[rb + 4], p[rb + 5]);
            unsigned a3 = pkrtz(p[rb + 6], p[rb + 7]);
            asm volatile("v_permlane32_swap_b32 %0, %1" : "+v"(a0), "+v"(a2));
            asm volatile("v_permlane32_swap_b32 %0, %1" : "+v"(a1), "+v"(a3));
            H8U4 pa;
            pa.u.x = a0; pa.u.y = a1; pa.u.z = a2; pa.u.w = a3;
            half8 vb = *(const half8*)(&Vb[(kt * 4 + m * 2 + h) * 256 + l31 * 8]);
            O = __builtin_amdgcn_mfma_f32_32x32x16_f16(pa.h, vb, O, 0, 0, 0);
        }
    }

    float tot = sum + __shfl_xor(sum, 32);
    if (h == 0) rsum[wave * 32 + l31] = 1.f / tot;
    __syncthreads();

    float4 r0 = *(const float4*)(&rsum[wave * 32 + 4 * h + 0]);
    float4 r1 = *(const float4*)(&rsum[wave * 32 + 4 * h + 8]);
    float4 r2 = *(const float4*)(&rsum[wave * 32 + 4 * h + 16]);
    float4 r3 = *(const float4*)(&rsum[wave * 32 + 4 * h + 24]);
    float rv[16] = {r0.x, r0.y, r0.z, r0.w, r1.x, r1.y, r1.z, r1.w,
                    r2.x, r2.y, r2.z, r2.w, r3.x, r3.y, r3.z, r3.w};

    _Float16* aop = ao + ((size_t)win * NSEQ + wave * 32) * C_ + head * DH + l31;
#pragma unroll
    for (int r = 0; r < 16; ++r) {
        int qp = (r & 3) + 8 * (r >> 2) + 4 * h;
        if (wave * 32 + qp < NSEQ)
            aop[(size_t)qp * C_] = (_Float16)(O[r] * rv[r]);
    }
}

// ---------------- Kernel 3: projection GEMM + bias + window reverse ----------------
// New epilogue: per-wave LDS transpose Ot[16ch][68] so output stores are
// 4 planes x 256B contiguous per instruction (dwordx4/lane) instead of 16x64B.
__global__ __launch_bounds__(256) void k_proj(
    const _Float16* __restrict__ ah, const _Float16* __restrict__ wh,
    const float* __restrict__ pb, float* __restrict__ out)
{
    __shared__ _Float16 As[64 * 264];
    __shared__ alignas(16) float Ot[4][16 * 68];
    const int tid = threadIdx.x;
    const int wave = tid >> 6, lane = tid & 63;
    const int l15 = lane & 15, g = lane >> 4;
    const long tok0 = (long)blockIdx.x * 64;

    {
        int r = tid >> 2, c8 = tid & 3;
        long tok = tok0 + r;
        int b = (int)(tok / DHW);
        int pos = (int)(tok - (long)b * DHW);
        int d = pos / 2304, rem = pos % 2304, hh = rem / 48, ww = rem % 48;
        int wi = (d / 6) * 64 + (hh / 6) * 8 + (ww / 6);
        int n = (d % 6) * 36 + (hh % 6) * 6 + (ww % 6);
        const _Float16* src = ah + ((size_t)(b * 512 + wi) * NSEQ + n) * C_;
        _Float16* dst = &As[r * 264];
#pragma unroll
        for (int i = 0; i < 8; ++i)
            *(half8*)(dst + c8 * 8 + i * 32) = *(const half8*)(src + c8 * 8 + i * 32);
    }
    __syncthreads();

    const int b0 = (int)(tok0 / DHW);
    const int pos0 = (int)(tok0 - (long)b0 * DHW);
    float* ob = out + (size_t)b0 * C_ * DHW + pos0;
    float* ow = &Ot[wave][0];

#pragma unroll
    for (int ct = 0; ct < 4; ++ct) {
        const int c0 = wave * 64 + ct * 16;
        half8 afr[8];
#pragma unroll
        for (int kc = 0; kc < 8; ++kc)
            afr[kc] = *(const half8*)(wh + (size_t)(c0 + l15) * C_ + kc * 32 + g * 8);
        float4 bq = *(const float4*)(pb + c0 + g * 4);
#pragma unroll
        for (int tt = 0; tt < 4; ++tt) {
            float4v o = {bq.x, bq.y, bq.z, bq.w};
#pragma unroll
            for (int kc = 0; kc < 8; ++kc) {
                half8 bfr = *(const half8*)(&As[(tt * 16 + l15) * 264 + kc * 32 + g * 8]);
                o = __builtin_amdgcn_mfma_f32_16x16x32_f16(afr[kc], bfr, o, 0, 0, 0);
            }
            // transpose-store into this wave's Ot: [local ch g*4+r][token tt*16+l15]
#pragma unroll
            for (int r = 0; r < 4; ++r)
                ow[(g * 4 + r) * 68 + tt * 16 + l15] = o[r];
        }
        // within-wave LDS RAW: DS pipe is in-order per wave; wait + pin schedule
        asm volatile("s_waitcnt lgkmcnt(0)" ::: "memory");
        __builtin_amdgcn_sched_barrier(0);
        // flush: lane reads float4 (4 consecutive tokens) of channel g+4*it
#pragma unroll
        for (int it = 0; it < 4; ++it) {
            const int chl = g + 4 * it;
            float4 v = *(const float4*)(&ow[chl * 68 + l15 * 4]);
            *(float4*)(ob + (size_t)(c0 + chl) * DHW + l15 * 4) = v;
        }
        __builtin_amdgcn_sched_barrier(0);
    }
}

extern "C" void kernel_launch(void* const* d_in, const int* in_sizes, int n_in,
                              void* d_out, int out_size, void* d_ws, size_t ws_size,
                              hipStream_t stream)
{
    const float* q_map  = (const float*)d_in[0];
    const float* k_map  = (const float*)d_in[1];
    const float* v_map  = (const float*)d_in[2];
    const float* lnq_w  = (const float*)d_in[3];
    const float* lnq_b  = (const float*)d_in[4];
    const float* lnkv_w = (const float*)d_in[5];
    const float* lnkv_b = (const float*)d_in[6];
    const float* proj_w = (const float*)d_in[7];
    const float* proj_b = (const float*)d_in[8];
    float* out = (float*)d_out;

    const size_t SZ = (size_t)NTOK * C_;
    _Float16* qh = (_Float16*)d_ws;
    _Float16* kh = qh + SZ;
    _Float16* vh = kh + SZ;
    _Float16* ah = vh + SZ;
    _Float16* wh = ah + SZ;

    k_convert_w<<<64, 256, 0, stream>>>(proj_w, wh);
    k_ln<<<dim3(3456, 3), 512, 0, stream>>>(q_map, k_map, v_map,
                                            lnq_w, lnq_b, lnkv_w, lnkv_b, qh, kh, vh);
    k_attn<<<8192, 448, 0, stream>>>(qh, kh, vh, ah);
    k_proj<<<3456, 256, 0, stream>>>(ah, wh, proj_b, out);
}